// Round 12
// baseline (742.035 us; speedup 1.0000x reference)
//
#include <hip/hip_runtime.h>
#include <math.h>

typedef _Float16 f16;
typedef _Float16 f16x4 __attribute__((ext_vector_type(4)));
typedef _Float16 f16x8 __attribute__((ext_vector_type(8)));
typedef float f32x4 __attribute__((ext_vector_type(4)));
typedef float f32x16 __attribute__((ext_vector_type(16)));

#define MFMA_F16 __builtin_amdgcn_mfma_f32_16x16x32_f16
#define MFMA32_F16 __builtin_amdgcn_mfma_f32_32x32x16_f16

namespace {
constexpr int kL = 4096;   // faces (queries)
constexpr int kS = 8192;   // edges (keys/values)
constexpr int kD = 256;    // embed dim
constexpr int kH = 2;      // heads
constexpr int kDH = 128;   // head dim
constexpr int kNL = 4;     // layers
constexpr int kNS = 16;    // S-dim splits in dense attention
constexpr float kScale = 0.08838834764831845f;  // 1/sqrt(128)
}

// ---------- fused f32->f16 conversion of all inputs (one dispatch) ----------
__global__ __launch_bounds__(256) void cvt_all_k(
    const float* __restrict__ edge, const float* __restrict__ face,
    const float* __restrict__ inw, const float* __restrict__ outw,
    f16* __restrict__ e16, f16* __restrict__ xa,
    f16* __restrict__ win16, f16* __restrict__ wout16) {
  for (int i = blockIdx.x * 256 + threadIdx.x; i < 1048576; i += 1024 * 256) {
    const float* src;
    f16* dst;
    int off;
    if (i < 524288) { src = edge; dst = e16; off = i; }
    else if (i < 786432) { src = face; dst = xa; off = i - 524288; }
    else if (i < 983040) { src = inw; dst = win16; off = i - 786432; }
    else { src = outw; dst = wout16; off = i - 983040; }
    float4 v = *(const float4*)(src + 4 * (size_t)off);
    f16x4 h;
    h[0] = (f16)v.x; h[1] = (f16)v.y; h[2] = (f16)v.z; h[3] = (f16)v.w;
    *(f16x4*)(dst + 4 * (size_t)off) = h;
  }
}

// Detect on-device element widths of loop (int32/int64) and mask (1/4/8 B).
__global__ __launch_bounds__(256) void detect_k(const unsigned int* __restrict__ loopw,
                                                const unsigned char* __restrict__ maskb,
                                                int* __restrict__ flags) {
  __shared__ unsigned int s[3];
  if (threadIdx.x < 3) s[threadIdx.x] = 0;
  __syncthreads();
  unsigned int orodd = 0;
  for (int i = 1 + 2 * threadIdx.x; i < 2048; i += 512) orodd |= loopw[i];
  unsigned int nz1 = 0, nz4 = 0;
  for (int i = threadIdx.x; i < 512; i += 256) {
    unsigned char b = maskb[i];
    if ((i & 3) != 0) nz1 |= b;
    if ((i & 7) == 4) nz4 |= b;
  }
  atomicOr(&s[0], orodd);
  atomicOr(&s[1], nz1);
  atomicOr(&s[2], nz4);
  __syncthreads();
  if (threadIdx.x == 0) {
    flags[0] = (s[0] == 0) ? 2 : 1;
    flags[1] = s[1] ? 1 : (s[2] ? 4 : 8);
  }
}

// ---------- GEMM core: 64x64 tile, A[M,K] @ W[N,K]^T ----------
__device__ __forceinline__ void gemm_core(const f16* __restrict__ A,
                                          const f16* __restrict__ W, int K,
                                          int m0, int n0, int r, int g,
                                          f32x4 acc[2][2]) {
  const f16* ap0 = A + (size_t)(m0 + r) * K + g * 8;
  const f16* ap1 = ap0 + (size_t)16 * K;
  const f16* bp0 = W + (size_t)(n0 + r) * K + g * 8;
  const f16* bp1 = bp0 + (size_t)16 * K;
#pragma unroll 8
  for (int kc = 0; kc < K; kc += 32) {
    f16x8 a0 = *(const f16x8*)(ap0 + kc);
    f16x8 a1 = *(const f16x8*)(ap1 + kc);
    f16x8 b0 = *(const f16x8*)(bp0 + kc);
    f16x8 b1 = *(const f16x8*)(bp1 + kc);
    acc[0][0] = MFMA_F16(a0, b0, acc[0][0], 0, 0, 0);
    acc[0][1] = MFMA_F16(a0, b1, acc[0][1], 0, 0, 0);
    acc[1][0] = MFMA_F16(a1, b0, acc[1][0], 0, 0, 0);
    acc[1][1] = MFMA_F16(a1, b1, acc[1][1], 0, 0, 0);
  }
}

// Fused Q/K/V projection. bid<256: Q = x@wq^T. Else KV = e@[wk;wv]^T.
// V-half blocks bounce their 64x64 tile through LDS to write Vt coalesced.
__global__ __launch_bounds__(256) void qkv_gemm_k(
    const f16* __restrict__ x, const f16* __restrict__ e16,
    const f16* __restrict__ wql, const float* __restrict__ biasl,
    f16* __restrict__ q16, f16* __restrict__ k16,
    f16* __restrict__ vt16, f16* __restrict__ v16) {
  __shared__ __align__(16) f16 Tl[64][72];
  const int lane = threadIdx.x & 63;
  const int wid = threadIdx.x >> 6;
  const int r = lane & 15, g = lane >> 4;
  const int bid = blockIdx.x;
  const bool qmode = bid < 256;
  int bx, by;
  const f16* A;
  const f16* W;
  const float* bias;
  if (qmode) {
    bx = bid & 63; by = bid >> 6;
    A = x; W = wql; bias = biasl;
  } else {
    int t = bid - 256;
    bx = t & 127; by = t >> 7;
    A = e16; W = wql + (size_t)kD * kD; bias = biasl + kD;
  }
  const int m0 = bx * 64 + (wid >> 1) * 32;
  const int n0 = by * 64 + (wid & 1) * 32;
  const bool vmode = !qmode && (by >= 4);
  f32x4 acc[2][2] = {};
  gemm_core(A, W, kD, m0, n0, r, g, acc);

#pragma unroll
  for (int mt = 0; mt < 2; ++mt)
#pragma unroll
    for (int nt = 0; nt < 2; ++nt) {
      int col = n0 + nt * 16 + r;
      float bv = bias[col];
#pragma unroll
      for (int i = 0; i < 4; ++i) {
        int row = m0 + mt * 16 + g * 4 + i;
        float v = acc[mt][nt][i] + bv;
        if (qmode) {
          q16[(size_t)row * kD + col] = (f16)v;
        } else if (!vmode) {
          k16[(size_t)row * 256 + col] = (f16)v;
        } else {
          int dv = col - 256;
          v16[(size_t)row * 256 + dv] = (f16)v;
          int nl = (wid & 1) * 32 + nt * 16 + r;
          int rl = (wid >> 1) * 32 + mt * 16 + g * 4 + i;
          Tl[nl][rl] = (f16)v;
        }
      }
    }
  if (vmode) {
    __syncthreads();
    const int dvb = (by - 4) * 64;
    const int key0 = bx * 64;
#pragma unroll
    for (int it = 0; it < 2; ++it) {
      int rowd = it * 32 + (threadIdx.x >> 3);
      int seg = (threadIdx.x & 7) * 8;
      *(f16x8*)&vt16[(size_t)(dvb + rowd) * kS + key0 + seg] =
          *(const f16x8*)&Tl[rowd][seg];
    }
  }
}

// Out-projection: C = A @ W^T + bias -> fp16 (and optionally f32 final out)
__global__ __launch_bounds__(256) void gemm_awt_k(
    const f16* __restrict__ A, const f16* __restrict__ W,
    const float* __restrict__ bias, f16* __restrict__ C16,
    float* __restrict__ C32, int M, int N, int K) {
  const int lane = threadIdx.x & 63;
  const int wid = threadIdx.x >> 6;
  const int r = lane & 15, g = lane >> 4;
  const int m0 = blockIdx.x * 64 + (wid >> 1) * 32;
  const int n0 = blockIdx.y * 64 + (wid & 1) * 32;
  f32x4 acc[2][2] = {};
  gemm_core(A, W, K, m0, n0, r, g, acc);
#pragma unroll
  for (int mt = 0; mt < 2; ++mt)
#pragma unroll
    for (int nt = 0; nt < 2; ++nt) {
      int col = n0 + nt * 16 + r;
      float bv = bias[col];
#pragma unroll
      for (int i = 0; i < 4; ++i) {
        int row = m0 + mt * 16 + g * 4 + i;
        float v = acc[mt][nt][i] + bv;
        C16[(size_t)row * N + col] = (f16)v;
        if (C32) C32[(size_t)row * N + col] = v;
      }
    }
}

// ---------- dense attention helpers ----------
__device__ __forceinline__ unsigned pkh(float a, float b) {
  auto h2 = __builtin_amdgcn_cvt_pkrtz(a, b);
  return __builtin_bit_cast(unsigned, h2);
}
__device__ __forceinline__ void pswap(unsigned a, unsigned b, unsigned& x,
                                      unsigned& y) {
  typedef int i32x2 __attribute__((ext_vector_type(2)));
  i32x2 rr = __builtin_amdgcn_permlane32_swap((int)a, (int)b, false, false);
  x = (unsigned)rr[0];
  y = (unsigned)rr[1];
}
__device__ __forceinline__ f16x8 build_pfrag(float p0, float p1, float p2,
                                             float p3, float p4, float p5,
                                             float p6, float p7) {
  unsigned a0 = pkh(p0, p1), b0 = pkh(p4, p5);
  unsigned a1 = pkh(p2, p3), b1 = pkh(p6, p7);
  unsigned w0, w1, w2, w3;
  pswap(a0, b0, w0, w2);
  pswap(a1, b1, w1, w3);
  union { unsigned u[4]; f16x8 v; } r;
  r.u[0] = w0; r.u[1] = w1; r.u[2] = w2; r.u[3] = w3;
  return r.v;
}

// ---------- dense attention: Q_w=64 (2 groups/wave) + XCD swizzle ----------
// Per-wave math = round-9/10-verified attn_dense5/6 (two 32-q groups share
// every K/V LDS fragment -> 2 MFMAs per ds_read, halving the LDS-read
// bottleneck measured in round 11). Grid/memory plumbing = round-11-verified
// attn_dense7 (XCD-aware decode, reg-staged dbuf, pswap f16x8 epilogue).
// Grid: 512 blocks = 16 q-tiles x 32 (h,z) groups; id%8 == g%8 pins all
// sharers of a K/V chunk to one XCD (4 chunks x 256KB per L2).
__global__ __launch_bounds__(256, 2) void attn_dense8_k(
    const f16* __restrict__ Q, const f16* __restrict__ Km,
    const f16* __restrict__ Vt,
    f16* __restrict__ numOut, float* __restrict__ denOut) {
  __shared__ __align__(16) f16 Kl[2][64 * 128];  // [key][d], XOR-swizzled
  __shared__ __align__(16) f16 Vl[2][128 * 64];  // [d][key], XOR-swizzled
  const int tid = threadIdx.x;
  const int lane = tid & 63, wid = tid >> 6;
  const int la = lane & 31, hi = lane >> 5;
  const int id = blockIdx.x;
  const int grp = id & 31;       // (h,z) group
  const int h = grp & 1;
  const int z = grp >> 1;
  const int bx = id >> 5;        // q-tile
  const int q0w = bx * 256 + wid * 64;
  const int sb0 = z * (kS / kNS);
  const int nt = (kS / kNS) / 64;  // 8

  // Q B-frags for two 32-q groups (col=la, k=hi*8+j)
  f16x8 qb[2][8];
#pragma unroll
  for (int g2 = 0; g2 < 2; ++g2)
#pragma unroll
    for (int kk = 0; kk < 8; ++kk)
      qb[g2][kk] = *(const f16x8*)(Q + (size_t)(q0w + g2 * 32 + la) * kD +
                                   h * kDH + kk * 16 + hi * 8);

  // staging addresses (pre-swizzled sources, linear-in-row LDS dests)
  int kSrc[4], kDst[4], vSrc[4], vDst[4];
#pragma unroll
  for (int p = 0; p < 4; ++p) {
    int m = wid * 16 + p * 4 + (lane >> 4);
    int s = lane & 15;
    kSrc[p] = (sb0 + m) * kD + h * kDH + 8 * (s ^ (m & 7));
    kDst[p] = m * 128 + 8 * s;
    int cv = p * 256 + tid;
    int d = cv >> 3, sv = cv & 7;
    vSrc[p] = (h * kDH + d) * kS + sb0 + 8 * (sv ^ (d & 7));
    vDst[p] = d * 64 + 8 * sv;
  }

  f32x16 o[2][4] = {};
  float den0 = 0.0f, den1 = 0.0f;
  f16x8 kst[4], vst[4];

#pragma unroll
  for (int p = 0; p < 4; ++p) {
    kst[p] = *(const f16x8*)(Km + kSrc[p]);
    vst[p] = *(const f16x8*)(Vt + vSrc[p]);
  }
#pragma unroll
  for (int p = 0; p < 4; ++p) {
    *(f16x8*)&Kl[0][kDst[p]] = kst[p];
    *(f16x8*)&Vl[0][vDst[p]] = vst[p];
  }
  __syncthreads();

  for (int t = 0; t < nt; ++t) {
    const int cur = t & 1;
    if (t + 1 < nt) {
#pragma unroll
      for (int p = 0; p < 4; ++p) {
        kst[p] = *(const f16x8*)(Km + kSrc[p] + (t + 1) * 64 * kD);
        vst[p] = *(const f16x8*)(Vt + vSrc[p] + (t + 1) * 64);
      }
    }

#pragma unroll
    for (int hf = 0; hf < 2; ++hf) {  // 32-key halves
      f32x16 s0 = {}, s1 = {};
      __builtin_amdgcn_s_setprio(1);
#pragma unroll
      for (int kk = 0; kk < 8; ++kk) {
        f16x8 kf = *(const f16x8*)&Kl[cur][(hf * 32 + la) * 128 +
                                           8 * ((2 * kk + hi) ^ (la & 7))];
        s0 = MFMA32_F16(kf, qb[0][kk], s0, 0, 0, 0);
        s1 = MFMA32_F16(kf, qb[1][kk], s1, 0, 0, 0);
      }
      __builtin_amdgcn_s_setprio(0);

      f32x16 p0, p1;
#pragma unroll
      for (int i = 0; i < 16; ++i) {
        p0[i] = __expf(s0[i] * kScale);
        p1[i] = __expf(s1[i] * kScale);
      }
#pragma unroll
      for (int i = 0; i < 16; ++i) {
        den0 += p0[i];
        den1 += p1[i];
      }

      f16x8 pf0[2], pf1[2];
      pf0[0] = build_pfrag(p0[0], p0[1], p0[2], p0[3], p0[4], p0[5], p0[6], p0[7]);
      pf0[1] = build_pfrag(p0[8], p0[9], p0[10], p0[11], p0[12], p0[13], p0[14], p0[15]);
      pf1[0] = build_pfrag(p1[0], p1[1], p1[2], p1[3], p1[4], p1[5], p1[6], p1[7]);
      pf1[1] = build_pfrag(p1[8], p1[9], p1[10], p1[11], p1[12], p1[13], p1[14], p1[15]);

      __builtin_amdgcn_s_setprio(1);
#pragma unroll
      for (int dt = 0; dt < 4; ++dt) {
        int d = dt * 32 + la;
#pragma unroll
        for (int ks = 0; ks < 2; ++ks) {
          f16x8 vf = *(const f16x8*)&Vl[cur][d * 64 +
                                             8 * (((hf * 2 + ks) * 2 + hi) ^ (d & 7))];
          o[0][dt] = MFMA32_F16(vf, pf0[ks], o[0][dt], 0, 0, 0);
          o[1][dt] = MFMA32_F16(vf, pf1[ks], o[1][dt], 0, 0, 0);
        }
      }
      __builtin_amdgcn_s_setprio(0);
    }

    if (t + 1 < nt) {
      const int nxt = cur ^ 1;
#pragma unroll
      for (int p = 0; p < 4; ++p) {
        *(f16x8*)&Kl[nxt][kDst[p]] = kst[p];
        *(f16x8*)&Vl[nxt][vDst[p]] = vst[p];
      }
      __syncthreads();
    }
  }

  // Epilogue (round-10-verified pswap regroup) -> f16x8 stores, [z][h][L][d]
  const size_t nbase = ((size_t)z * kH + h) * kL + q0w;
#pragma unroll
  for (int g2 = 0; g2 < 2; ++g2) {
    const size_t rowb = (nbase + g2 * 32 + la) * kDH;
#pragma unroll
    for (int dt = 0; dt < 4; ++dt) {
      unsigned u01 = pkh(o[g2][dt][0], o[g2][dt][1]);
      unsigned u23 = pkh(o[g2][dt][2], o[g2][dt][3]);
      unsigned u89 = pkh(o[g2][dt][4], o[g2][dt][5]);
      unsigned uab = pkh(o[g2][dt][6], o[g2][dt][7]);
      unsigned w0, w1, w2, w3;
      pswap(u01, u89, w0, w2);
      pswap(u23, uab, w1, w3);
      union { unsigned u[4]; f16x8 v; } r1;
      r1.u[0] = w0; r1.u[1] = w1; r1.u[2] = w2; r1.u[3] = w3;
      *(f16x8*)&numOut[rowb + dt * 32 + hi * 8] = r1.v;

      unsigned v01 = pkh(o[g2][dt][8], o[g2][dt][9]);
      unsigned v23 = pkh(o[g2][dt][10], o[g2][dt][11]);
      unsigned v89 = pkh(o[g2][dt][12], o[g2][dt][13]);
      unsigned vab = pkh(o[g2][dt][14], o[g2][dt][15]);
      unsigned x0, x1, x2, x3;
      pswap(v01, v89, x0, x2);
      pswap(v23, vab, x1, x3);
      union { unsigned u[4]; f16x8 v; } r2;
      r2.u[0] = x0; r2.u[1] = x1; r2.u[2] = x2; r2.u[3] = x3;
      *(f16x8*)&numOut[rowb + dt * 32 + 16 + hi * 8] = r2.v;
    }
  }
  float dq0 = den0 + __shfl_xor(den0, 32);
  float dq1 = den1 + __shfl_xor(den1, 32);
  if (lane < 32) {
    const size_t dbase = ((size_t)z * kH + h) * kL + q0w;
    denOut[dbase + lane] = dq0;
    denOut[dbase + 32 + lane] = dq1;
  }
}

// ---------- fused correction + combine (coalesced numb reads) ----------
__global__ __launch_bounds__(256) void corrcomb_k(
    const unsigned int* __restrict__ loopw, const unsigned char* __restrict__ maskb,
    const int* __restrict__ flags,
    const f16* __restrict__ Q, const f16* __restrict__ Km,
    const f16* __restrict__ V,
    const f16* __restrict__ numb, const float* __restrict__ denb,
    f16* __restrict__ out16) {
  __shared__ float cvL[4][128];
  __shared__ float csL[4];
  const int lane = threadIdx.x & 63;
  const int wid = threadIdx.x >> 6;
  const int w = blockIdx.x * 4 + wid;
  const int f = w >> 1, h = w & 1;
  const int lstride = flags[0];
  const int mstride = flags[1];

  int idx = -1, valid = 0;
  if (lane < 32) {
    idx = (int)loopw[(size_t)(f * 32 + lane) * lstride];
    valid = maskb[(size_t)f * mstride] ? 1 : 0;
  }
#pragma unroll
  for (int j = 0; j < 32; ++j) {
    int oidx = __shfl(idx, j);
    if (lane < 32 && j < lane && oidx == idx) valid = 0;
  }

  const size_t qb = (size_t)f * kD + h * kDH + 2 * lane;
  const float qa = (float)Q[qb];
  const float qbv = (float)Q[qb + 1];
  float s0 = 0.0f, cv0 = 0.0f, cv1 = 0.0f;
  for (int e = 0; e < 32; ++e) {
    int ei = __shfl(idx, e);
    int ev = __shfl(valid, e);
    if (!ev) continue;
    size_t kb = (size_t)ei * kD + h * kDH + 2 * lane;
    float part = qa * (float)Km[kb] + qbv * (float)Km[kb + 1];
#pragma unroll
    for (int m = 1; m < 64; m <<= 1) part += __shfl_xor(part, m);
    float pe = __expf(part * kScale);
    s0 += pe;
    cv0 += pe * (float)V[kb];
    cv1 += pe * (float)V[kb + 1];
  }
  cvL[wid][2 * lane] = cv0;
  cvL[wid][2 * lane + 1] = cv1;
  if (lane == 0) csL[wid] = s0;
  __syncthreads();

#pragma unroll
  for (int e = 0; e < 2; ++e) {
    int idx2 = e * 256 + threadIdx.x;
    int floc = idx2 >> 8;
    int c = idx2 & 255;
    int h2 = c >> 7;
    int d = c & 127;
    int widx = floc * 2 + h2;
    int fabs_ = blockIdx.x * 2 + floc;
    float n = -cvL[widx][d];
    float dn = -csL[widx];
#pragma unroll
    for (int z = 0; z < kNS; ++z) {
      n += (float)numb[((size_t)(z * kH + h2) * kL + fabs_) * kDH + d];
      dn += denb[((size_t)z * kH + h2) * kL + fabs_];
    }
    out16[(size_t)fabs_ * kD + h2 * kDH + d] = (f16)(n / dn);
  }
}

extern "C" void kernel_launch(void* const* d_in, const int* in_sizes, int n_in,
                              void* d_out, int out_size, void* d_ws, size_t ws_size,
                              hipStream_t stream) {
  const unsigned int* loopw = (const unsigned int*)d_in[0];
  const unsigned char* fmask = (const unsigned char*)d_in[1];
  const float* edge = (const float*)d_in[2];
  const float* face = (const float*)d_in[3];
  const float* inw = (const float*)d_in[4];
  const float* inb = (const float*)d_in[5];
  const float* outw = (const float*)d_in[6];
  const float* outb = (const float*)d_in[7];
  float* out = (float*)d_out;

  char* p = (char*)d_ws;
  auto alloc = [&](size_t bytes) {
    char* q = p;
    p += (bytes + 255) & ~(size_t)255;
    return q;
  };
  int* flags = (int*)alloc(256);
  f16* e16 = (f16*)alloc((size_t)kS * kD * 2);
  f16* win16 = (f16*)alloc((size_t)kNL * 3 * kD * kD * 2);
  f16* wout16 = (f16*)alloc((size_t)kNL * kD * kD * 2);
  f16* xa = (f16*)alloc((size_t)kL * kD * 2);
  f16* xb = (f16*)alloc((size_t)kL * kD * 2);
  f16* q16 = (f16*)alloc((size_t)kL * kD * 2);
  f16* k16 = (f16*)alloc((size_t)kS * kD * 2);
  f16* v16 = (f16*)alloc((size_t)kS * kD * 2);
  f16* vt16 = (f16*)alloc((size_t)kS * kD * 2);
  f16* ao16 = (f16*)alloc((size_t)kL * kD * 2);
  f16* numb = (f16*)alloc((size_t)kNS * kH * kL * kDH * 2);
  float* denb = (float*)alloc((size_t)kNS * kH * kL * 4);

  detect_k<<<1, 256, 0, stream>>>(loopw, fmask, flags);
  cvt_all_k<<<1024, 256, 0, stream>>>(edge, face, inw, outw, e16, xa, win16,
                                      wout16);

  f16* x = xa;
  f16* xn = xb;
  for (int l = 0; l < kNL; ++l) {
    const f16* wql = win16 + (size_t)l * 3 * kD * kD;
    qkv_gemm_k<<<1280, 256, 0, stream>>>(x, e16, wql, inb + l * 3 * kD, q16,
                                         k16, vt16, v16);
    attn_dense8_k<<<512, 256, 0, stream>>>(q16, k16, vt16, numb, denb);
    corrcomb_k<<<kL / 2, 256, 0, stream>>>(loopw, fmask, flags, q16, k16, v16,
                                           numb, denb, ao16);
    gemm_awt_k<<<dim3(kL / 64, kD / 64), 256, 0, stream>>>(
        ao16, wout16 + (size_t)l * kD * kD, outb + l * kD, xn,
        (l == kNL - 1) ? out : nullptr, kL, kD, kD);
    f16* tmp = x;
    x = xn;
    xn = tmp;
  }
}

// Round 13
// 444.002 us; speedup vs baseline: 1.6712x; 1.6712x over previous
//
#include <hip/hip_runtime.h>
#include <math.h>

typedef _Float16 f16;
typedef _Float16 f16x4 __attribute__((ext_vector_type(4)));
typedef _Float16 f16x8 __attribute__((ext_vector_type(8)));
typedef float f32x4 __attribute__((ext_vector_type(4)));
typedef float f32x16 __attribute__((ext_vector_type(16)));

#define MFMA_F16 __builtin_amdgcn_mfma_f32_16x16x32_f16
#define MFMA32_F16 __builtin_amdgcn_mfma_f32_32x32x16_f16

namespace {
constexpr int kL = 4096;   // faces (queries)
constexpr int kS = 8192;   // edges (keys/values)
constexpr int kD = 256;    // embed dim
constexpr int kH = 2;      // heads
constexpr int kDH = 128;   // head dim
constexpr int kNL = 4;     // layers
constexpr int kNS = 8;     // S-dim splits in dense attention
constexpr float kScale = 0.08838834764831845f;  // 1/sqrt(128)
}

// ---------- fused f32->f16 conversion of all inputs (one dispatch) ----------
__global__ __launch_bounds__(256) void cvt_all_k(
    const float* __restrict__ edge, const float* __restrict__ face,
    const float* __restrict__ inw, const float* __restrict__ outw,
    f16* __restrict__ e16, f16* __restrict__ xa,
    f16* __restrict__ win16, f16* __restrict__ wout16) {
  for (int i = blockIdx.x * 256 + threadIdx.x; i < 1048576; i += 1024 * 256) {
    const float* src;
    f16* dst;
    int off;
    if (i < 524288) { src = edge; dst = e16; off = i; }
    else if (i < 786432) { src = face; dst = xa; off = i - 524288; }
    else if (i < 983040) { src = inw; dst = win16; off = i - 786432; }
    else { src = outw; dst = wout16; off = i - 983040; }
    float4 v = *(const float4*)(src + 4 * (size_t)off);
    f16x4 h;
    h[0] = (f16)v.x; h[1] = (f16)v.y; h[2] = (f16)v.z; h[3] = (f16)v.w;
    *(f16x4*)(dst + 4 * (size_t)off) = h;
  }
}

// Detect on-device element widths of loop (int32/int64) and mask (1/4/8 B).
__global__ __launch_bounds__(256) void detect_k(const unsigned int* __restrict__ loopw,
                                                const unsigned char* __restrict__ maskb,
                                                int* __restrict__ flags) {
  __shared__ unsigned int s[3];
  if (threadIdx.x < 3) s[threadIdx.x] = 0;
  __syncthreads();
  unsigned int orodd = 0;
  for (int i = 1 + 2 * threadIdx.x; i < 2048; i += 512) orodd |= loopw[i];
  unsigned int nz1 = 0, nz4 = 0;
  for (int i = threadIdx.x; i < 512; i += 256) {
    unsigned char b = maskb[i];
    if ((i & 3) != 0) nz1 |= b;
    if ((i & 7) == 4) nz4 |= b;
  }
  atomicOr(&s[0], orodd);
  atomicOr(&s[1], nz1);
  atomicOr(&s[2], nz4);
  __syncthreads();
  if (threadIdx.x == 0) {
    flags[0] = (s[0] == 0) ? 2 : 1;
    flags[1] = s[1] ? 1 : (s[2] ? 4 : 8);
  }
}

// ---------- GEMM core: 64x64 tile, A[M,K] @ W[N,K]^T ----------
__device__ __forceinline__ void gemm_core(const f16* __restrict__ A,
                                          const f16* __restrict__ W, int K,
                                          int m0, int n0, int r, int g,
                                          f32x4 acc[2][2]) {
  const f16* ap0 = A + (size_t)(m0 + r) * K + g * 8;
  const f16* ap1 = ap0 + (size_t)16 * K;
  const f16* bp0 = W + (size_t)(n0 + r) * K + g * 8;
  const f16* bp1 = bp0 + (size_t)16 * K;
#pragma unroll 8
  for (int kc = 0; kc < K; kc += 32) {
    f16x8 a0 = *(const f16x8*)(ap0 + kc);
    f16x8 a1 = *(const f16x8*)(ap1 + kc);
    f16x8 b0 = *(const f16x8*)(bp0 + kc);
    f16x8 b1 = *(const f16x8*)(bp1 + kc);
    acc[0][0] = MFMA_F16(a0, b0, acc[0][0], 0, 0, 0);
    acc[0][1] = MFMA_F16(a0, b1, acc[0][1], 0, 0, 0);
    acc[1][0] = MFMA_F16(a1, b0, acc[1][0], 0, 0, 0);
    acc[1][1] = MFMA_F16(a1, b1, acc[1][1], 0, 0, 0);
  }
}

// Fused Q/K/V projection. bid<256: Q = x@wq^T. Else KV = e@[wk;wv]^T.
// V-half blocks bounce their 64x64 tile through LDS to write Vt coalesced.
__global__ __launch_bounds__(256) void qkv_gemm_k(
    const f16* __restrict__ x, const f16* __restrict__ e16,
    const f16* __restrict__ wql, const float* __restrict__ biasl,
    f16* __restrict__ q16, f16* __restrict__ k16,
    f16* __restrict__ vt16, f16* __restrict__ v16) {
  __shared__ __align__(16) f16 Tl[64][72];
  const int lane = threadIdx.x & 63;
  const int wid = threadIdx.x >> 6;
  const int r = lane & 15, g = lane >> 4;
  const int bid = blockIdx.x;
  const bool qmode = bid < 256;
  int bx, by;
  const f16* A;
  const f16* W;
  const float* bias;
  if (qmode) {
    bx = bid & 63; by = bid >> 6;
    A = x; W = wql; bias = biasl;
  } else {
    int t = bid - 256;
    bx = t & 127; by = t >> 7;
    A = e16; W = wql + (size_t)kD * kD; bias = biasl + kD;
  }
  const int m0 = bx * 64 + (wid >> 1) * 32;
  const int n0 = by * 64 + (wid & 1) * 32;
  const bool vmode = !qmode && (by >= 4);
  f32x4 acc[2][2] = {};
  gemm_core(A, W, kD, m0, n0, r, g, acc);

#pragma unroll
  for (int mt = 0; mt < 2; ++mt)
#pragma unroll
    for (int nt = 0; nt < 2; ++nt) {
      int col = n0 + nt * 16 + r;
      float bv = bias[col];
#pragma unroll
      for (int i = 0; i < 4; ++i) {
        int row = m0 + mt * 16 + g * 4 + i;
        float v = acc[mt][nt][i] + bv;
        if (qmode) {
          q16[(size_t)row * kD + col] = (f16)v;
        } else if (!vmode) {
          k16[(size_t)row * 256 + col] = (f16)v;
        } else {
          int dv = col - 256;
          v16[(size_t)row * 256 + dv] = (f16)v;
          int nl = (wid & 1) * 32 + nt * 16 + r;
          int rl = (wid >> 1) * 32 + mt * 16 + g * 4 + i;
          Tl[nl][rl] = (f16)v;
        }
      }
    }
  if (vmode) {
    __syncthreads();
    const int dvb = (by - 4) * 64;
    const int key0 = bx * 64;
#pragma unroll
    for (int it = 0; it < 2; ++it) {
      int rowd = it * 32 + (threadIdx.x >> 3);
      int seg = (threadIdx.x & 7) * 8;
      *(f16x8*)&vt16[(size_t)(dvb + rowd) * kS + key0 + seg] =
          *(const f16x8*)&Tl[rowd][seg];
    }
  }
}

// Out-projection: C = A @ W^T + bias -> fp16 (and optionally f32 final out)
__global__ __launch_bounds__(256) void gemm_awt_k(
    const f16* __restrict__ A, const f16* __restrict__ W,
    const float* __restrict__ bias, f16* __restrict__ C16,
    float* __restrict__ C32, int M, int N, int K) {
  const int lane = threadIdx.x & 63;
  const int wid = threadIdx.x >> 6;
  const int r = lane & 15, g = lane >> 4;
  const int m0 = blockIdx.x * 64 + (wid >> 1) * 32;
  const int n0 = blockIdx.y * 64 + (wid & 1) * 32;
  f32x4 acc[2][2] = {};
  gemm_core(A, W, K, m0, n0, r, g, acc);
#pragma unroll
  for (int mt = 0; mt < 2; ++mt)
#pragma unroll
    for (int nt = 0; nt < 2; ++nt) {
      int col = n0 + nt * 16 + r;
      float bv = bias[col];
#pragma unroll
      for (int i = 0; i < 4; ++i) {
        int row = m0 + mt * 16 + g * 4 + i;
        float v = acc[mt][nt][i] + bv;
        C16[(size_t)row * N + col] = (f16)v;
        if (C32) C32[(size_t)row * N + col] = v;
      }
    }
}

// ---------- dense attention helpers ----------
__device__ __forceinline__ unsigned pkh(float a, float b) {
  auto h2 = __builtin_amdgcn_cvt_pkrtz(a, b);
  return __builtin_bit_cast(unsigned, h2);
}
__device__ __forceinline__ void pswap(unsigned a, unsigned b, unsigned& x,
                                      unsigned& y) {
  typedef int i32x2 __attribute__((ext_vector_type(2)));
  i32x2 rr = __builtin_amdgcn_permlane32_swap((int)a, (int)b, false, false);
  x = (unsigned)rr[0];
  y = (unsigned)rr[1];
}
__device__ __forceinline__ f16x8 build_pfrag(float p0, float p1, float p2,
                                             float p3, float p4, float p5,
                                             float p6, float p7) {
  unsigned a0 = pkh(p0, p1), b0 = pkh(p4, p5);
  unsigned a1 = pkh(p2, p3), b1 = pkh(p6, p7);
  unsigned w0, w1, w2, w3;
  pswap(a0, b0, w0, w2);
  pswap(a1, b1, w1, w3);
  union { unsigned u[4]; f16x8 v; } r;
  r.u[0] = w0; r.u[1] = w1; r.u[2] = w2; r.u[3] = w3;
  return r.v;
}

// ---------- dense attention: round-11-verified attn_dense7 (45.6 us) ------
__global__ __launch_bounds__(256, 2) void attn_dense7_k(
    const f16* __restrict__ Q, const f16* __restrict__ Km,
    const f16* __restrict__ Vt,
    f16* __restrict__ numOut, float* __restrict__ denOut) {
  __shared__ __align__(16) f16 Kl[2][64 * 128];  // [key][d], XOR-swizzled
  __shared__ __align__(16) f16 Vl[2][128 * 64];  // [d][key], XOR-swizzled
  const int tid = threadIdx.x;
  const int lane = tid & 63, wid = tid >> 6;
  const int la = lane & 31, hi = lane >> 5;
  const int id = blockIdx.x;
  const int grp = id & 15;
  const int h = grp & 1;
  const int z = grp >> 1;
  const int bx = id >> 4;
  const int q0w = bx * 128 + wid * 32;
  const int sb0 = z * (kS / kNS);
  const int nt = (kS / kNS) / 64;  // 16

  f16x8 qb[8];
#pragma unroll
  for (int kk = 0; kk < 8; ++kk)
    qb[kk] = *(const f16x8*)(Q + (size_t)(q0w + la) * kD + h * kDH + kk * 16 +
                             hi * 8);

  int kSrc[4], kDst[4], vSrc[4], vDst[4];
#pragma unroll
  for (int p = 0; p < 4; ++p) {
    int m = wid * 16 + p * 4 + (lane >> 4);
    int s = lane & 15;
    kSrc[p] = (sb0 + m) * kD + h * kDH + 8 * (s ^ (m & 7));
    kDst[p] = m * 128 + 8 * s;
    int cv = p * 256 + tid;
    int d = cv >> 3, sv = cv & 7;
    vSrc[p] = (h * kDH + d) * kS + sb0 + 8 * (sv ^ (d & 7));
    vDst[p] = d * 64 + 8 * sv;
  }

  f32x16 o0 = {}, o1 = {}, o2 = {}, o3 = {};
  float den = 0.0f;
  f16x8 kst[4], vst[4];

#pragma unroll
  for (int p = 0; p < 4; ++p) {
    kst[p] = *(const f16x8*)(Km + kSrc[p]);
    vst[p] = *(const f16x8*)(Vt + vSrc[p]);
  }
#pragma unroll
  for (int p = 0; p < 4; ++p) {
    *(f16x8*)&Kl[0][kDst[p]] = kst[p];
    *(f16x8*)&Vl[0][vDst[p]] = vst[p];
  }
  __syncthreads();

  for (int t = 0; t < nt; ++t) {
    const int cur = t & 1;
    if (t + 1 < nt) {
#pragma unroll
      for (int p = 0; p < 4; ++p) {
        kst[p] = *(const f16x8*)(Km + kSrc[p] + (t + 1) * 64 * kD);
        vst[p] = *(const f16x8*)(Vt + vSrc[p] + (t + 1) * 64);
      }
    }

    f32x16 st0 = {}, st1 = {};
    __builtin_amdgcn_s_setprio(1);
#pragma unroll
    for (int kk = 0; kk < 8; ++kk) {
      int sl = 8 * ((kk * 2 + hi) ^ (la & 7));
      f16x8 k0 = *(const f16x8*)&Kl[cur][la * 128 + sl];
      f16x8 k1 = *(const f16x8*)&Kl[cur][(32 + la) * 128 + sl];
      st0 = MFMA32_F16(k0, qb[kk], st0, 0, 0, 0);
      st1 = MFMA32_F16(k1, qb[kk], st1, 0, 0, 0);
    }
    __builtin_amdgcn_s_setprio(0);

    f32x16 pe0, pe1;
#pragma unroll
    for (int i = 0; i < 16; ++i) {
      pe0[i] = __expf(st0[i] * kScale);
      pe1[i] = __expf(st1[i] * kScale);
    }
#pragma unroll
    for (int i = 0; i < 16; ++i) den += pe0[i] + pe1[i];

    f16x8 pf[4];
    pf[0] = build_pfrag(pe0[0], pe0[1], pe0[2], pe0[3], pe0[4], pe0[5], pe0[6], pe0[7]);
    pf[1] = build_pfrag(pe0[8], pe0[9], pe0[10], pe0[11], pe0[12], pe0[13], pe0[14], pe0[15]);
    pf[2] = build_pfrag(pe1[0], pe1[1], pe1[2], pe1[3], pe1[4], pe1[5], pe1[6], pe1[7]);
    pf[3] = build_pfrag(pe1[8], pe1[9], pe1[10], pe1[11], pe1[12], pe1[13], pe1[14], pe1[15]);

    __builtin_amdgcn_s_setprio(1);
#pragma unroll
    for (int dt = 0; dt < 4; ++dt) {
      int d = dt * 32 + la;
      f32x16* op = (dt == 0) ? &o0 : (dt == 1) ? &o1 : (dt == 2) ? &o2 : &o3;
#pragma unroll
      for (int ks = 0; ks < 4; ++ks) {
        f16x8 vf = *(const f16x8*)&Vl[cur][d * 64 + 8 * ((ks * 2 + hi) ^ (d & 7))];
        *op = MFMA32_F16(vf, pf[ks], *op, 0, 0, 0);
      }
    }
    __builtin_amdgcn_s_setprio(0);

    if (t + 1 < nt) {
      const int nxt = cur ^ 1;
#pragma unroll
      for (int p = 0; p < 4; ++p) {
        *(f16x8*)&Kl[nxt][kDst[p]] = kst[p];
        *(f16x8*)&Vl[nxt][vDst[p]] = vst[p];
      }
      __syncthreads();
    }
  }

  const size_t nbase = ((size_t)z * kH + h) * kL + q0w;
  const size_t rowb = (nbase + la) * kDH;
#pragma unroll
  for (int dt = 0; dt < 4; ++dt) {
    const f32x16* op = (dt == 0) ? &o0 : (dt == 1) ? &o1 : (dt == 2) ? &o2 : &o3;
    unsigned u01 = pkh((*op)[0], (*op)[1]);
    unsigned u23 = pkh((*op)[2], (*op)[3]);
    unsigned u89 = pkh((*op)[4], (*op)[5]);
    unsigned uab = pkh((*op)[6], (*op)[7]);
    unsigned w0, w1, w2, w3;
    pswap(u01, u89, w0, w2);
    pswap(u23, uab, w1, w3);
    union { unsigned u[4]; f16x8 v; } r1;
    r1.u[0] = w0; r1.u[1] = w1; r1.u[2] = w2; r1.u[3] = w3;
    *(f16x8*)&numOut[rowb + dt * 32 + hi * 8] = r1.v;

    unsigned v01 = pkh((*op)[8], (*op)[9]);
    unsigned v23 = pkh((*op)[10], (*op)[11]);
    unsigned v89 = pkh((*op)[12], (*op)[13]);
    unsigned vab = pkh((*op)[14], (*op)[15]);
    unsigned x0, x1, x2, x3;
    pswap(v01, v89, x0, x2);
    pswap(v23, vab, x1, x3);
    union { unsigned u[4]; f16x8 v; } r2;
    r2.u[0] = x0; r2.u[1] = x1; r2.u[2] = x2; r2.u[3] = x3;
    *(f16x8*)&numOut[rowb + dt * 32 + 16 + hi * 8] = r2.v;
  }
  float dq = den + __shfl_xor(den, 32);
  if (lane < 32)
    denOut[((size_t)z * kH + h) * kL + q0w + lane] = dq;
}

// ---------- fused correction + combine (edge-parallel correction) ----------
// Lane = (edge e = lane>>1, d-half = lane&1). Full 64-d partial dot per lane
// in parallel (vs round-11's serial 32x wave-reduce chain); invalid/duplicate
// edges get pe=0. PV stays edge-serial but is only shfl+load+fma per edge.
__global__ __launch_bounds__(256) void corrcomb_k(
    const unsigned int* __restrict__ loopw, const unsigned char* __restrict__ maskb,
    const int* __restrict__ flags,
    const f16* __restrict__ Q, const f16* __restrict__ Km,
    const f16* __restrict__ V,
    const f16* __restrict__ numb, const float* __restrict__ denb,
    f16* __restrict__ out16) {
  __shared__ float cvL[4][128];
  __shared__ float csL[4];
  const int lane = threadIdx.x & 63;
  const int wid = threadIdx.x >> 6;
  const int w = blockIdx.x * 4 + wid;
  const int f = w >> 1, h = w & 1;
  const int lstride = flags[0];
  const int mstride = flags[1];
  const int e = lane >> 1, half = lane & 1;

  int idxe = (int)loopw[(size_t)(f * 32 + e) * lstride];
  int valid = maskb[(size_t)f * mstride] ? 1 : 0;
#pragma unroll
  for (int j = 0; j < 32; ++j) {
    int oidx = __shfl(idxe, 2 * j);
    if (j < e && oidx == idxe) valid = 0;  // first-occurrence dedupe
  }

  // q . k_e over this lane's 64-d half (vectorized, all edges in parallel)
  const f16* qp = Q + (size_t)f * kD + h * kDH + half * 64;
  const f16* kp = Km + (size_t)idxe * kD + h * kDH + half * 64;
  float part = 0.0f;
#pragma unroll
  for (int v = 0; v < 8; ++v) {
    f16x8 qv = *(const f16x8*)(qp + v * 8);
    f16x8 kv = *(const f16x8*)(kp + v * 8);
#pragma unroll
    for (int i = 0; i < 8; ++i) part += (float)qv[i] * (float)kv[i];
  }
  part += __shfl_xor(part, 1);  // combine d-halves within the pair
  float pe = valid ? __expf(part * kScale) : 0.0f;

  // csum = sum over one lane per edge (even lanes)
  float r = pe;
#pragma unroll
  for (int m = 2; m < 64; m <<= 1) r += __shfl_xor(r, m);
  if (lane == 0) csL[wid] = r;

  // cvec: edge-serial accumulation, pe/idx broadcast (uniform branch)
  float cv0 = 0.0f, cv1 = 0.0f;
  for (int e2 = 0; e2 < 32; ++e2) {
    float pb = __shfl(pe, 2 * e2);
    int ei = __shfl(idxe, 2 * e2);
    if (pb != 0.0f) {
      size_t kb = (size_t)ei * kD + h * kDH + 2 * lane;
      cv0 += pb * (float)V[kb];
      cv1 += pb * (float)V[kb + 1];
    }
  }
  cvL[wid][2 * lane] = cv0;
  cvL[wid][2 * lane + 1] = cv1;
  __syncthreads();

#pragma unroll
  for (int ee = 0; ee < 2; ++ee) {
    int idx2 = ee * 256 + threadIdx.x;
    int floc = idx2 >> 8;
    int c = idx2 & 255;
    int h2 = c >> 7;
    int d = c & 127;
    int widx = floc * 2 + h2;
    int fabs_ = blockIdx.x * 2 + floc;
    float n = -cvL[widx][d];
    float dn = -csL[widx];
#pragma unroll
    for (int z = 0; z < kNS; ++z) {
      n += (float)numb[((size_t)(z * kH + h2) * kL + fabs_) * kDH + d];
      dn += denb[((size_t)z * kH + h2) * kL + fabs_];
    }
    out16[(size_t)fabs_ * kD + h2 * kDH + d] = (f16)(n / dn);
  }
}

extern "C" void kernel_launch(void* const* d_in, const int* in_sizes, int n_in,
                              void* d_out, int out_size, void* d_ws, size_t ws_size,
                              hipStream_t stream) {
  const unsigned int* loopw = (const unsigned int*)d_in[0];
  const unsigned char* fmask = (const unsigned char*)d_in[1];
  const float* edge = (const float*)d_in[2];
  const float* face = (const float*)d_in[3];
  const float* inw = (const float*)d_in[4];
  const float* inb = (const float*)d_in[5];
  const float* outw = (const float*)d_in[6];
  const float* outb = (const float*)d_in[7];
  float* out = (float*)d_out;

  char* p = (char*)d_ws;
  auto alloc = [&](size_t bytes) {
    char* q = p;
    p += (bytes + 255) & ~(size_t)255;
    return q;
  };
  int* flags = (int*)alloc(256);
  f16* e16 = (f16*)alloc((size_t)kS * kD * 2);
  f16* win16 = (f16*)alloc((size_t)kNL * 3 * kD * kD * 2);
  f16* wout16 = (f16*)alloc((size_t)kNL * kD * kD * 2);
  f16* xa = (f16*)alloc((size_t)kL * kD * 2);
  f16* xb = (f16*)alloc((size_t)kL * kD * 2);
  f16* q16 = (f16*)alloc((size_t)kL * kD * 2);
  f16* k16 = (f16*)alloc((size_t)kS * kD * 2);
  f16* v16 = (f16*)alloc((size_t)kS * kD * 2);
  f16* vt16 = (f16*)alloc((size_t)kS * kD * 2);
  f16* ao16 = (f16*)alloc((size_t)kL * kD * 2);
  f16* numb = (f16*)alloc((size_t)kNS * kH * kL * kDH * 2);
  float* denb = (float*)alloc((size_t)kNS * kH * kL * 4);

  detect_k<<<1, 256, 0, stream>>>(loopw, fmask, flags);
  cvt_all_k<<<1024, 256, 0, stream>>>(edge, face, inw, outw, e16, xa, win16,
                                      wout16);

  f16* x = xa;
  f16* xn = xb;
  for (int l = 0; l < kNL; ++l) {
    const f16* wql = win16 + (size_t)l * 3 * kD * kD;
    qkv_gemm_k<<<1280, 256, 0, stream>>>(x, e16, wql, inb + l * 3 * kD, q16,
                                         k16, vt16, v16);
    attn_dense7_k<<<512, 256, 0, stream>>>(q16, k16, vt16, numb, denb);
    corrcomb_k<<<kL / 2, 256, 0, stream>>>(loopw, fmask, flags, q16, k16, v16,
                                           numb, denb, ao16);
    gemm_awt_k<<<dim3(kL / 64, kD / 64), 256, 0, stream>>>(
        ao16, wout16 + (size_t)l * kD * kD, outb + l * kD, xn,
        (l == kNL - 1) ? out : nullptr, kL, kD, kD);
    f16* tmp = x;
    x = xn;
    xn = tmp;
  }
}

// Round 14
// 427.906 us; speedup vs baseline: 1.7341x; 1.0376x over previous
//
#include <hip/hip_runtime.h>
#include <math.h>

typedef _Float16 f16;
typedef _Float16 f16x4 __attribute__((ext_vector_type(4)));
typedef _Float16 f16x8 __attribute__((ext_vector_type(8)));
typedef float f32x4 __attribute__((ext_vector_type(4)));
typedef float f32x16 __attribute__((ext_vector_type(16)));

#define MFMA_F16 __builtin_amdgcn_mfma_f32_16x16x32_f16
#define MFMA32_F16 __builtin_amdgcn_mfma_f32_32x32x16_f16

namespace {
constexpr int kL = 4096;   // faces (queries)
constexpr int kS = 8192;   // edges (keys/values)
constexpr int kD = 256;    // embed dim
constexpr int kH = 2;      // heads
constexpr int kDH = 128;   // head dim
constexpr int kNL = 4;     // layers
constexpr int kNS = 8;     // S-dim splits in dense attention
constexpr float kScale = 0.08838834764831845f;  // 1/sqrt(128)
}

// ---------- fused f32->f16 conversion of all inputs (one dispatch) ----------
__global__ __launch_bounds__(256) void cvt_all_k(
    const float* __restrict__ edge, const float* __restrict__ face,
    const float* __restrict__ inw, const float* __restrict__ outw,
    f16* __restrict__ e16, f16* __restrict__ xa,
    f16* __restrict__ win16, f16* __restrict__ wout16) {
  for (int i = blockIdx.x * 256 + threadIdx.x; i < 1048576; i += 1024 * 256) {
    const float* src;
    f16* dst;
    int off;
    if (i < 524288) { src = edge; dst = e16; off = i; }
    else if (i < 786432) { src = face; dst = xa; off = i - 524288; }
    else if (i < 983040) { src = inw; dst = win16; off = i - 786432; }
    else { src = outw; dst = wout16; off = i - 983040; }
    float4 v = *(const float4*)(src + 4 * (size_t)off);
    f16x4 h;
    h[0] = (f16)v.x; h[1] = (f16)v.y; h[2] = (f16)v.z; h[3] = (f16)v.w;
    *(f16x4*)(dst + 4 * (size_t)off) = h;
  }
}

// Detect on-device element widths of loop (int32/int64) and mask (1/4/8 B).
__global__ __launch_bounds__(256) void detect_k(const unsigned int* __restrict__ loopw,
                                                const unsigned char* __restrict__ maskb,
                                                int* __restrict__ flags) {
  __shared__ unsigned int s[3];
  if (threadIdx.x < 3) s[threadIdx.x] = 0;
  __syncthreads();
  unsigned int orodd = 0;
  for (int i = 1 + 2 * threadIdx.x; i < 2048; i += 512) orodd |= loopw[i];
  unsigned int nz1 = 0, nz4 = 0;
  for (int i = threadIdx.x; i < 512; i += 256) {
    unsigned char b = maskb[i];
    if ((i & 3) != 0) nz1 |= b;
    if ((i & 7) == 4) nz4 |= b;
  }
  atomicOr(&s[0], orodd);
  atomicOr(&s[1], nz1);
  atomicOr(&s[2], nz4);
  __syncthreads();
  if (threadIdx.x == 0) {
    flags[0] = (s[0] == 0) ? 2 : 1;
    flags[1] = s[1] ? 1 : (s[2] ? 4 : 8);
  }
}

// ---------- GEMM core: 64x64 tile, A[M,K] @ W[N,K]^T ----------
__device__ __forceinline__ void gemm_core(const f16* __restrict__ A,
                                          const f16* __restrict__ W, int K,
                                          int m0, int n0, int r, int g,
                                          f32x4 acc[2][2]) {
  const f16* ap0 = A + (size_t)(m0 + r) * K + g * 8;
  const f16* ap1 = ap0 + (size_t)16 * K;
  const f16* bp0 = W + (size_t)(n0 + r) * K + g * 8;
  const f16* bp1 = bp0 + (size_t)16 * K;
#pragma unroll 8
  for (int kc = 0; kc < K; kc += 32) {
    f16x8 a0 = *(const f16x8*)(ap0 + kc);
    f16x8 a1 = *(const f16x8*)(ap1 + kc);
    f16x8 b0 = *(const f16x8*)(bp0 + kc);
    f16x8 b1 = *(const f16x8*)(bp1 + kc);
    acc[0][0] = MFMA_F16(a0, b0, acc[0][0], 0, 0, 0);
    acc[0][1] = MFMA_F16(a0, b1, acc[0][1], 0, 0, 0);
    acc[1][0] = MFMA_F16(a1, b0, acc[1][0], 0, 0, 0);
    acc[1][1] = MFMA_F16(a1, b1, acc[1][1], 0, 0, 0);
  }
}

// Fused Q/K/V projection. bid<256: Q = x@wq^T. Else KV = e@[wk;wv]^T.
// V-half blocks bounce their 64x64 tile through LDS to write Vt coalesced.
__global__ __launch_bounds__(256) void qkv_gemm_k(
    const f16* __restrict__ x, const f16* __restrict__ e16,
    const f16* __restrict__ wql, const float* __restrict__ biasl,
    f16* __restrict__ q16, f16* __restrict__ k16,
    f16* __restrict__ vt16, f16* __restrict__ v16) {
  __shared__ __align__(16) f16 Tl[64][72];
  const int lane = threadIdx.x & 63;
  const int wid = threadIdx.x >> 6;
  const int r = lane & 15, g = lane >> 4;
  const int bid = blockIdx.x;
  const bool qmode = bid < 256;
  int bx, by;
  const f16* A;
  const f16* W;
  const float* bias;
  if (qmode) {
    bx = bid & 63; by = bid >> 6;
    A = x; W = wql; bias = biasl;
  } else {
    int t = bid - 256;
    bx = t & 127; by = t >> 7;
    A = e16; W = wql + (size_t)kD * kD; bias = biasl + kD;
  }
  const int m0 = bx * 64 + (wid >> 1) * 32;
  const int n0 = by * 64 + (wid & 1) * 32;
  const bool vmode = !qmode && (by >= 4);
  f32x4 acc[2][2] = {};
  gemm_core(A, W, kD, m0, n0, r, g, acc);

#pragma unroll
  for (int mt = 0; mt < 2; ++mt)
#pragma unroll
    for (int nt = 0; nt < 2; ++nt) {
      int col = n0 + nt * 16 + r;
      float bv = bias[col];
#pragma unroll
      for (int i = 0; i < 4; ++i) {
        int row = m0 + mt * 16 + g * 4 + i;
        float v = acc[mt][nt][i] + bv;
        if (qmode) {
          q16[(size_t)row * kD + col] = (f16)v;
        } else if (!vmode) {
          k16[(size_t)row * 256 + col] = (f16)v;
        } else {
          int dv = col - 256;
          v16[(size_t)row * 256 + dv] = (f16)v;
          int nl = (wid & 1) * 32 + nt * 16 + r;
          int rl = (wid >> 1) * 32 + mt * 16 + g * 4 + i;
          Tl[nl][rl] = (f16)v;
        }
      }
    }
  if (vmode) {
    __syncthreads();
    const int dvb = (by - 4) * 64;
    const int key0 = bx * 64;
#pragma unroll
    for (int it = 0; it < 2; ++it) {
      int rowd = it * 32 + (threadIdx.x >> 3);
      int seg = (threadIdx.x & 7) * 8;
      *(f16x8*)&vt16[(size_t)(dvb + rowd) * kS + key0 + seg] =
          *(const f16x8*)&Tl[rowd][seg];
    }
  }
}

// Out-projection: C = A @ W^T + bias -> fp16 (and optionally f32 final out)
__global__ __launch_bounds__(256) void gemm_awt_k(
    const f16* __restrict__ A, const f16* __restrict__ W,
    const float* __restrict__ bias, f16* __restrict__ C16,
    float* __restrict__ C32, int M, int N, int K) {
  const int lane = threadIdx.x & 63;
  const int wid = threadIdx.x >> 6;
  const int r = lane & 15, g = lane >> 4;
  const int m0 = blockIdx.x * 64 + (wid >> 1) * 32;
  const int n0 = blockIdx.y * 64 + (wid & 1) * 32;
  f32x4 acc[2][2] = {};
  gemm_core(A, W, K, m0, n0, r, g, acc);
#pragma unroll
  for (int mt = 0; mt < 2; ++mt)
#pragma unroll
    for (int nt = 0; nt < 2; ++nt) {
      int col = n0 + nt * 16 + r;
      float bv = bias[col];
#pragma unroll
      for (int i = 0; i < 4; ++i) {
        int row = m0 + mt * 16 + g * 4 + i;
        float v = acc[mt][nt][i] + bv;
        C16[(size_t)row * N + col] = (f16)v;
        if (C32) C32[(size_t)row * N + col] = v;
      }
    }
}

// ---------- dense attention helpers ----------
__device__ __forceinline__ unsigned pkh(float a, float b) {
  auto h2 = __builtin_amdgcn_cvt_pkrtz(a, b);
  return __builtin_bit_cast(unsigned, h2);
}
__device__ __forceinline__ void pswap(unsigned a, unsigned b, unsigned& x,
                                      unsigned& y) {
  typedef int i32x2 __attribute__((ext_vector_type(2)));
  i32x2 rr = __builtin_amdgcn_permlane32_swap((int)a, (int)b, false, false);
  x = (unsigned)rr[0];
  y = (unsigned)rr[1];
}
__device__ __forceinline__ f16x8 build_pfrag(float p0, float p1, float p2,
                                             float p3, float p4, float p5,
                                             float p6, float p7) {
  unsigned a0 = pkh(p0, p1), b0 = pkh(p4, p5);
  unsigned a1 = pkh(p2, p3), b1 = pkh(p6, p7);
  unsigned w0, w1, w2, w3;
  pswap(a0, b0, w0, w2);
  pswap(a1, b1, w1, w3);
  union { unsigned u[4]; f16x8 v; } r;
  r.u[0] = w0; r.u[1] = w1; r.u[2] = w2; r.u[3] = w3;
  return r.v;
}

// ---------- dense attention: round-11-verified attn_dense7 (45.6 us) ------
__global__ __launch_bounds__(256, 2) void attn_dense7_k(
    const f16* __restrict__ Q, const f16* __restrict__ Km,
    const f16* __restrict__ Vt,
    f16* __restrict__ numOut, float* __restrict__ denOut) {
  __shared__ __align__(16) f16 Kl[2][64 * 128];  // [key][d], XOR-swizzled
  __shared__ __align__(16) f16 Vl[2][128 * 64];  // [d][key], XOR-swizzled
  const int tid = threadIdx.x;
  const int lane = tid & 63, wid = tid >> 6;
  const int la = lane & 31, hi = lane >> 5;
  const int id = blockIdx.x;
  const int grp = id & 15;
  const int h = grp & 1;
  const int z = grp >> 1;
  const int bx = id >> 4;
  const int q0w = bx * 128 + wid * 32;
  const int sb0 = z * (kS / kNS);
  const int nt = (kS / kNS) / 64;  // 16

  f16x8 qb[8];
#pragma unroll
  for (int kk = 0; kk < 8; ++kk)
    qb[kk] = *(const f16x8*)(Q + (size_t)(q0w + la) * kD + h * kDH + kk * 16 +
                             hi * 8);

  int kSrc[4], kDst[4], vSrc[4], vDst[4];
#pragma unroll
  for (int p = 0; p < 4; ++p) {
    int m = wid * 16 + p * 4 + (lane >> 4);
    int s = lane & 15;
    kSrc[p] = (sb0 + m) * kD + h * kDH + 8 * (s ^ (m & 7));
    kDst[p] = m * 128 + 8 * s;
    int cv = p * 256 + tid;
    int d = cv >> 3, sv = cv & 7;
    vSrc[p] = (h * kDH + d) * kS + sb0 + 8 * (sv ^ (d & 7));
    vDst[p] = d * 64 + 8 * sv;
  }

  f32x16 o0 = {}, o1 = {}, o2 = {}, o3 = {};
  float den = 0.0f;
  f16x8 kst[4], vst[4];

#pragma unroll
  for (int p = 0; p < 4; ++p) {
    kst[p] = *(const f16x8*)(Km + kSrc[p]);
    vst[p] = *(const f16x8*)(Vt + vSrc[p]);
  }
#pragma unroll
  for (int p = 0; p < 4; ++p) {
    *(f16x8*)&Kl[0][kDst[p]] = kst[p];
    *(f16x8*)&Vl[0][vDst[p]] = vst[p];
  }
  __syncthreads();

  for (int t = 0; t < nt; ++t) {
    const int cur = t & 1;
    if (t + 1 < nt) {
#pragma unroll
      for (int p = 0; p < 4; ++p) {
        kst[p] = *(const f16x8*)(Km + kSrc[p] + (t + 1) * 64 * kD);
        vst[p] = *(const f16x8*)(Vt + vSrc[p] + (t + 1) * 64);
      }
    }

    f32x16 st0 = {}, st1 = {};
    __builtin_amdgcn_s_setprio(1);
#pragma unroll
    for (int kk = 0; kk < 8; ++kk) {
      int sl = 8 * ((kk * 2 + hi) ^ (la & 7));
      f16x8 k0 = *(const f16x8*)&Kl[cur][la * 128 + sl];
      f16x8 k1 = *(const f16x8*)&Kl[cur][(32 + la) * 128 + sl];
      st0 = MFMA32_F16(k0, qb[kk], st0, 0, 0, 0);
      st1 = MFMA32_F16(k1, qb[kk], st1, 0, 0, 0);
    }
    __builtin_amdgcn_s_setprio(0);

    f32x16 pe0, pe1;
#pragma unroll
    for (int i = 0; i < 16; ++i) {
      pe0[i] = __expf(st0[i] * kScale);
      pe1[i] = __expf(st1[i] * kScale);
    }
#pragma unroll
    for (int i = 0; i < 16; ++i) den += pe0[i] + pe1[i];

    f16x8 pf[4];
    pf[0] = build_pfrag(pe0[0], pe0[1], pe0[2], pe0[3], pe0[4], pe0[5], pe0[6], pe0[7]);
    pf[1] = build_pfrag(pe0[8], pe0[9], pe0[10], pe0[11], pe0[12], pe0[13], pe0[14], pe0[15]);
    pf[2] = build_pfrag(pe1[0], pe1[1], pe1[2], pe1[3], pe1[4], pe1[5], pe1[6], pe1[7]);
    pf[3] = build_pfrag(pe1[8], pe1[9], pe1[10], pe1[11], pe1[12], pe1[13], pe1[14], pe1[15]);

    __builtin_amdgcn_s_setprio(1);
#pragma unroll
    for (int dt = 0; dt < 4; ++dt) {
      int d = dt * 32 + la;
      f32x16* op = (dt == 0) ? &o0 : (dt == 1) ? &o1 : (dt == 2) ? &o2 : &o3;
#pragma unroll
      for (int ks = 0; ks < 4; ++ks) {
        f16x8 vf = *(const f16x8*)&Vl[cur][d * 64 + 8 * ((ks * 2 + hi) ^ (d & 7))];
        *op = MFMA32_F16(vf, pf[ks], *op, 0, 0, 0);
      }
    }
    __builtin_amdgcn_s_setprio(0);

    if (t + 1 < nt) {
      const int nxt = cur ^ 1;
#pragma unroll
      for (int p = 0; p < 4; ++p) {
        *(f16x8*)&Kl[nxt][kDst[p]] = kst[p];
        *(f16x8*)&Vl[nxt][vDst[p]] = vst[p];
      }
      __syncthreads();
    }
  }

  const size_t nbase = ((size_t)z * kH + h) * kL + q0w;
  const size_t rowb = (nbase + la) * kDH;
#pragma unroll
  for (int dt = 0; dt < 4; ++dt) {
    const f32x16* op = (dt == 0) ? &o0 : (dt == 1) ? &o1 : (dt == 2) ? &o2 : &o3;
    unsigned u01 = pkh((*op)[0], (*op)[1]);
    unsigned u23 = pkh((*op)[2], (*op)[3]);
    unsigned u89 = pkh((*op)[4], (*op)[5]);
    unsigned uab = pkh((*op)[6], (*op)[7]);
    unsigned w0, w1, w2, w3;
    pswap(u01, u89, w0, w2);
    pswap(u23, uab, w1, w3);
    union { unsigned u[4]; f16x8 v; } r1;
    r1.u[0] = w0; r1.u[1] = w1; r1.u[2] = w2; r1.u[3] = w3;
    *(f16x8*)&numOut[rowb + dt * 32 + hi * 8] = r1.v;

    unsigned v01 = pkh((*op)[8], (*op)[9]);
    unsigned v23 = pkh((*op)[10], (*op)[11]);
    unsigned v89 = pkh((*op)[12], (*op)[13]);
    unsigned vab = pkh((*op)[14], (*op)[15]);
    unsigned x0, x1, x2, x3;
    pswap(v01, v89, x0, x2);
    pswap(v23, vab, x1, x3);
    union { unsigned u[4]; f16x8 v; } r2;
    r2.u[0] = x0; r2.u[1] = x1; r2.u[2] = x2; r2.u[3] = x3;
    *(f16x8*)&numOut[rowb + dt * 32 + 16 + hi * 8] = r2.v;
  }
  float dq = den + __shfl_xor(den, 32);
  if (lane < 32)
    denOut[((size_t)z * kH + h) * kL + q0w + lane] = dq;
}

// ---------- fused correction + combine ----------
// Round-11 gather pattern (all 64 lanes on ONE edge row -> 256B coalesced
// per edge; round-13's per-lane-row version scattered 32 cache lines per
// load and regressed). Serial-chain cost halved via 2-edge ILP unroll:
// two independent dot/butterfly/exp chains in flight per iteration.
__global__ __launch_bounds__(256) void corrcomb_k(
    const unsigned int* __restrict__ loopw, const unsigned char* __restrict__ maskb,
    const int* __restrict__ flags,
    const f16* __restrict__ Q, const f16* __restrict__ Km,
    const f16* __restrict__ V,
    const f16* __restrict__ numb, const float* __restrict__ denb,
    f16* __restrict__ out16) {
  __shared__ float cvL[4][128];
  __shared__ float csL[4];
  const int lane = threadIdx.x & 63;
  const int wid = threadIdx.x >> 6;
  const int w = blockIdx.x * 4 + wid;
  const int f = w >> 1, h = w & 1;
  const int lstride = flags[0];
  const int mstride = flags[1];

  int idx = -1, valid = 0;
  if (lane < 32) {
    idx = (int)loopw[(size_t)(f * 32 + lane) * lstride];
    valid = maskb[(size_t)f * mstride] ? 1 : 0;
  }
#pragma unroll
  for (int j = 0; j < 32; ++j) {
    int oidx = __shfl(idx, j);
    if (lane < 32 && j < lane && oidx == idx) valid = 0;
  }

  const size_t qb = (size_t)f * kD + h * kDH + 2 * lane;
  const float qa = (float)Q[qb];
  const float qbv = (float)Q[qb + 1];
  float s0 = 0.0f, cv0 = 0.0f, cv1 = 0.0f;

  for (int e = 0; e < 32; e += 2) {
    int ei0 = __shfl(idx, e);
    int ev0 = __shfl(valid, e);
    int ei1 = __shfl(idx, e + 1);
    int ev1 = __shfl(valid, e + 1);
    size_t kb0 = (size_t)ei0 * kD + h * kDH + 2 * lane;
    size_t kb1 = (size_t)ei1 * kD + h * kDH + 2 * lane;
    float p0 = 0.0f, p1 = 0.0f;
    if (ev0) p0 = qa * (float)Km[kb0] + qbv * (float)Km[kb0 + 1];
    if (ev1) p1 = qa * (float)Km[kb1] + qbv * (float)Km[kb1 + 1];
#pragma unroll
    for (int m = 1; m < 64; m <<= 1) {
      p0 += __shfl_xor(p0, m);
      p1 += __shfl_xor(p1, m);
    }
    if (ev0) {
      float pe = __expf(p0 * kScale);
      s0 += pe;
      cv0 += pe * (float)V[kb0];
      cv1 += pe * (float)V[kb0 + 1];
    }
    if (ev1) {
      float pe = __expf(p1 * kScale);
      s0 += pe;
      cv0 += pe * (float)V[kb1];
      cv1 += pe * (float)V[kb1 + 1];
    }
  }
  cvL[wid][2 * lane] = cv0;
  cvL[wid][2 * lane + 1] = cv1;
  if (lane == 0) csL[wid] = s0;
  __syncthreads();

#pragma unroll
  for (int e = 0; e < 2; ++e) {
    int idx2 = e * 256 + threadIdx.x;
    int floc = idx2 >> 8;
    int c = idx2 & 255;
    int h2 = c >> 7;
    int d = c & 127;
    int widx = floc * 2 + h2;
    int fabs_ = blockIdx.x * 2 + floc;
    float n = -cvL[widx][d];
    float dn = -csL[widx];
#pragma unroll
    for (int z = 0; z < kNS; ++z) {
      n += (float)numb[((size_t)(z * kH + h2) * kL + fabs_) * kDH + d];
      dn += denb[((size_t)z * kH + h2) * kL + fabs_];
    }
    out16[(size_t)fabs_ * kD + h2 * kDH + d] = (f16)(n / dn);
  }
}

extern "C" void kernel_launch(void* const* d_in, const int* in_sizes, int n_in,
                              void* d_out, int out_size, void* d_ws, size_t ws_size,
                              hipStream_t stream) {
  const unsigned int* loopw = (const unsigned int*)d_in[0];
  const unsigned char* fmask = (const unsigned char*)d_in[1];
  const float* edge = (const float*)d_in[2];
  const float* face = (const float*)d_in[3];
  const float* inw = (const float*)d_in[4];
  const float* inb = (const float*)d_in[5];
  const float* outw = (const float*)d_in[6];
  const float* outb = (const float*)d_in[7];
  float* out = (float*)d_out;

  char* p = (char*)d_ws;
  auto alloc = [&](size_t bytes) {
    char* q = p;
    p += (bytes + 255) & ~(size_t)255;
    return q;
  };
  int* flags = (int*)alloc(256);
  f16* e16 = (f16*)alloc((size_t)kS * kD * 2);
  f16* win16 = (f16*)alloc((size_t)kNL * 3 * kD * kD * 2);
  f16* wout16 = (f16*)alloc((size_t)kNL * kD * kD * 2);
  f16* xa = (f16*)alloc((size_t)kL * kD * 2);
  f16* xb = (f16*)alloc((size_t)kL * kD * 2);
  f16* q16 = (f16*)alloc((size_t)kL * kD * 2);
  f16* k16 = (f16*)alloc((size_t)kS * kD * 2);
  f16* v16 = (f16*)alloc((size_t)kS * kD * 2);
  f16* vt16 = (f16*)alloc((size_t)kS * kD * 2);
  f16* ao16 = (f16*)alloc((size_t)kL * kD * 2);
  f16* numb = (f16*)alloc((size_t)kNS * kH * kL * kDH * 2);
  float* denb = (float*)alloc((size_t)kNS * kH * kL * 4);

  detect_k<<<1, 256, 0, stream>>>(loopw, fmask, flags);
  cvt_all_k<<<1024, 256, 0, stream>>>(edge, face, inw, outw, e16, xa, win16,
                                      wout16);

  f16* x = xa;
  f16* xn = xb;
  for (int l = 0; l < kNL; ++l) {
    const f16* wql = win16 + (size_t)l * 3 * kD * kD;
    qkv_gemm_k<<<1280, 256, 0, stream>>>(x, e16, wql, inb + l * 3 * kD, q16,
                                         k16, vt16, v16);
    attn_dense7_k<<<512, 256, 0, stream>>>(q16, k16, vt16, numb, denb);
    corrcomb_k<<<kL / 2, 256, 0, stream>>>(loopw, fmask, flags, q16, k16, v16,
                                           numb, denb, ao16);
    gemm_awt_k<<<dim3(kL / 64, kD / 64), 256, 0, stream>>>(
        ao16, wout16 + (size_t)l * kD * kD, outb + l * kD, xn,
        (l == kNL - 1) ? out : nullptr, kL, kD, kD);
    f16* tmp = x;
    x = xn;
    xn = tmp;
  }
}

// Round 15
// 411.638 us; speedup vs baseline: 1.8026x; 1.0395x over previous
//
#include <hip/hip_runtime.h>
#include <math.h>

typedef _Float16 f16;
typedef _Float16 f16x4 __attribute__((ext_vector_type(4)));
typedef _Float16 f16x8 __attribute__((ext_vector_type(8)));
typedef float f32x4 __attribute__((ext_vector_type(4)));
typedef float f32x16 __attribute__((ext_vector_type(16)));

#define MFMA_F16 __builtin_amdgcn_mfma_f32_16x16x32_f16
#define MFMA32_F16 __builtin_amdgcn_mfma_f32_32x32x16_f16

namespace {
constexpr int kL = 4096;   // faces (queries)
constexpr int kS = 8192;   // edges (keys/values)
constexpr int kD = 256;    // embed dim
constexpr int kH = 2;      // heads
constexpr int kDH = 128;   // head dim
constexpr int kNL = 4;     // layers
constexpr int kNS = 8;     // S-dim splits in dense attention
constexpr float kScale = 0.08838834764831845f;  // 1/sqrt(128)
}

// ---------- fused f32->f16 conversion of all inputs (one dispatch) ----------
__global__ __launch_bounds__(256) void cvt_all_k(
    const float* __restrict__ edge, const float* __restrict__ face,
    const float* __restrict__ inw, const float* __restrict__ outw,
    f16* __restrict__ e16, f16* __restrict__ xa,
    f16* __restrict__ win16, f16* __restrict__ wout16) {
  for (int i = blockIdx.x * 256 + threadIdx.x; i < 1048576; i += 1024 * 256) {
    const float* src;
    f16* dst;
    int off;
    if (i < 524288) { src = edge; dst = e16; off = i; }
    else if (i < 786432) { src = face; dst = xa; off = i - 524288; }
    else if (i < 983040) { src = inw; dst = win16; off = i - 786432; }
    else { src = outw; dst = wout16; off = i - 983040; }
    float4 v = *(const float4*)(src + 4 * (size_t)off);
    f16x4 h;
    h[0] = (f16)v.x; h[1] = (f16)v.y; h[2] = (f16)v.z; h[3] = (f16)v.w;
    *(f16x4*)(dst + 4 * (size_t)off) = h;
  }
}

// Detect on-device element widths of loop (int32/int64) and mask (1/4/8 B).
__global__ __launch_bounds__(256) void detect_k(const unsigned int* __restrict__ loopw,
                                                const unsigned char* __restrict__ maskb,
                                                int* __restrict__ flags) {
  __shared__ unsigned int s[3];
  if (threadIdx.x < 3) s[threadIdx.x] = 0;
  __syncthreads();
  unsigned int orodd = 0;
  for (int i = 1 + 2 * threadIdx.x; i < 2048; i += 512) orodd |= loopw[i];
  unsigned int nz1 = 0, nz4 = 0;
  for (int i = threadIdx.x; i < 512; i += 256) {
    unsigned char b = maskb[i];
    if ((i & 3) != 0) nz1 |= b;
    if ((i & 7) == 4) nz4 |= b;
  }
  atomicOr(&s[0], orodd);
  atomicOr(&s[1], nz1);
  atomicOr(&s[2], nz4);
  __syncthreads();
  if (threadIdx.x == 0) {
    flags[0] = (s[0] == 0) ? 2 : 1;
    flags[1] = s[1] ? 1 : (s[2] ? 4 : 8);
  }
}

// ---------- weight composition: wqo_l = wq_l . wo_{l-1}, b' = wq_l.bo + bq --
// q_l = x_l @ wq^T + bq, x_l = O_{l-1} @ wo^T + bo  =>
// q_l = O_{l-1} @ wqo^T + b'  (exact in f32; removes 3 out-proj GEMMs)
__global__ __launch_bounds__(256) void compose_k(
    const float* __restrict__ inw, const float* __restrict__ inb,
    const float* __restrict__ outw, const float* __restrict__ outb,
    f16* __restrict__ wqo, float* __restrict__ bprime) {
  const int lc = blockIdx.y;  // 0..2 -> layer l = lc+1
  const int i = blockIdx.x;   // output row
  const int j = threadIdx.x;  // output col
  const int l = lc + 1;
  const float* wq = inw + (size_t)l * 3 * kD * kD;   // wq_l [256][256]
  const float* wo = outw + (size_t)lc * kD * kD;     // wo_{l-1}
  float acc = 0.0f;
  for (int k = 0; k < kD; ++k)
    acc += wq[i * kD + k] * wo[k * kD + j];  // wo row read coalesced over j
  wqo[((size_t)lc * kD + i) * kD + j] = (f16)acc;

  float t = wq[i * kD + j] * outb[lc * kD + j];
  __shared__ float red[4];
#pragma unroll
  for (int m = 1; m < 64; m <<= 1) t += __shfl_xor(t, m);
  if ((threadIdx.x & 63) == 0) red[threadIdx.x >> 6] = t;
  __syncthreads();
  if (threadIdx.x == 0)
    bprime[lc * kD + i] = red[0] + red[1] + red[2] + red[3] + inb[l * 3 * kD + i];
}

// ---------- GEMM core: 64x64 tile, A[M,K] @ W[N,K]^T ----------
__device__ __forceinline__ void gemm_core(const f16* __restrict__ A,
                                          const f16* __restrict__ W, int K,
                                          int m0, int n0, int r, int g,
                                          f32x4 acc[2][2]) {
  const f16* ap0 = A + (size_t)(m0 + r) * K + g * 8;
  const f16* ap1 = ap0 + (size_t)16 * K;
  const f16* bp0 = W + (size_t)(n0 + r) * K + g * 8;
  const f16* bp1 = bp0 + (size_t)16 * K;
#pragma unroll 8
  for (int kc = 0; kc < K; kc += 32) {
    f16x8 a0 = *(const f16x8*)(ap0 + kc);
    f16x8 a1 = *(const f16x8*)(ap1 + kc);
    f16x8 b0 = *(const f16x8*)(bp0 + kc);
    f16x8 b1 = *(const f16x8*)(bp1 + kc);
    acc[0][0] = MFMA_F16(a0, b0, acc[0][0], 0, 0, 0);
    acc[0][1] = MFMA_F16(a0, b1, acc[0][1], 0, 0, 0);
    acc[1][0] = MFMA_F16(a1, b0, acc[1][0], 0, 0, 0);
    acc[1][1] = MFMA_F16(a1, b1, acc[1][1], 0, 0, 0);
  }
}

// All 4 layers' K/V in one dispatch: KV_l = e16 @ [wk_l;wv_l]^T + b.
// V-half blocks bounce their 64x64 tile through LDS to write Vt coalesced.
__global__ __launch_bounds__(256) void kvall_gemm_k(
    const f16* __restrict__ e16, const f16* __restrict__ win16,
    const float* __restrict__ inb,
    f16* __restrict__ k16all, f16* __restrict__ vt16all,
    f16* __restrict__ v16all) {
  __shared__ __align__(16) f16 Tl[64][72];
  const int lane = threadIdx.x & 63;
  const int wid = threadIdx.x >> 6;
  const int r = lane & 15, g = lane >> 4;
  const int bid = blockIdx.x;
  const int l = bid >> 10;
  const int t = bid & 1023;
  const int bx = t & 127, by = t >> 7;  // by 0-3: K cols, 4-7: V cols
  const f16* W = win16 + (size_t)l * 3 * kD * kD + (size_t)kD * kD;
  const float* bias = inb + l * 3 * kD + kD;
  f16* k16 = k16all + (size_t)l * kS * kD;
  f16* vt16 = vt16all + (size_t)l * kS * kD;
  f16* v16 = v16all + (size_t)l * kS * kD;

  const int m0 = bx * 64 + (wid >> 1) * 32;
  const int n0 = by * 64 + (wid & 1) * 32;
  const bool vmode = (by >= 4);
  f32x4 acc[2][2] = {};
  gemm_core(e16, W, kD, m0, n0, r, g, acc);

#pragma unroll
  for (int mt = 0; mt < 2; ++mt)
#pragma unroll
    for (int nt = 0; nt < 2; ++nt) {
      int col = n0 + nt * 16 + r;
      float bv = bias[col];
#pragma unroll
      for (int i = 0; i < 4; ++i) {
        int row = m0 + mt * 16 + g * 4 + i;
        float v = acc[mt][nt][i] + bv;
        if (!vmode) {
          k16[(size_t)row * 256 + col] = (f16)v;
        } else {
          int dv = col - 256;
          v16[(size_t)row * 256 + dv] = (f16)v;
          int nl = (wid & 1) * 32 + nt * 16 + r;
          int rl = (wid >> 1) * 32 + mt * 16 + g * 4 + i;
          Tl[nl][rl] = (f16)v;
        }
      }
    }
  if (vmode) {
    __syncthreads();
    const int dvb = (by - 4) * 64;
    const int key0 = bx * 64;
#pragma unroll
    for (int it = 0; it < 2; ++it) {
      int rowd = it * 32 + (threadIdx.x >> 3);
      int seg = (threadIdx.x & 7) * 8;
      *(f16x8*)&vt16[(size_t)(dvb + rowd) * kS + key0 + seg] =
          *(const f16x8*)&Tl[rowd][seg];
    }
  }
}

// C = A @ W^T + bias -> fp16 (and optionally f32 final out). Grid (M/64,N/64).
__global__ __launch_bounds__(256) void gemm_awt_k(
    const f16* __restrict__ A, const f16* __restrict__ W,
    const float* __restrict__ bias, f16* __restrict__ C16,
    float* __restrict__ C32, int M, int N, int K) {
  const int lane = threadIdx.x & 63;
  const int wid = threadIdx.x >> 6;
  const int r = lane & 15, g = lane >> 4;
  const int m0 = blockIdx.x * 64 + (wid >> 1) * 32;
  const int n0 = blockIdx.y * 64 + (wid & 1) * 32;
  f32x4 acc[2][2] = {};
  gemm_core(A, W, K, m0, n0, r, g, acc);
#pragma unroll
  for (int mt = 0; mt < 2; ++mt)
#pragma unroll
    for (int nt = 0; nt < 2; ++nt) {
      int col = n0 + nt * 16 + r;
      float bv = bias[col];
#pragma unroll
      for (int i = 0; i < 4; ++i) {
        int row = m0 + mt * 16 + g * 4 + i;
        float v = acc[mt][nt][i] + bv;
        C16[(size_t)row * N + col] = (f16)v;
        if (C32) C32[(size_t)row * N + col] = v;
      }
    }
}

// ---------- dense attention helpers ----------
__device__ __forceinline__ unsigned pkh(float a, float b) {
  auto h2 = __builtin_amdgcn_cvt_pkrtz(a, b);
  return __builtin_bit_cast(unsigned, h2);
}
__device__ __forceinline__ void pswap(unsigned a, unsigned b, unsigned& x,
                                      unsigned& y) {
  typedef int i32x2 __attribute__((ext_vector_type(2)));
  i32x2 rr = __builtin_amdgcn_permlane32_swap((int)a, (int)b, false, false);
  x = (unsigned)rr[0];
  y = (unsigned)rr[1];
}
__device__ __forceinline__ f16x8 build_pfrag(float p0, float p1, float p2,
                                             float p3, float p4, float p5,
                                             float p6, float p7) {
  unsigned a0 = pkh(p0, p1), b0 = pkh(p4, p5);
  unsigned a1 = pkh(p2, p3), b1 = pkh(p6, p7);
  unsigned w0, w1, w2, w3;
  pswap(a0, b0, w0, w2);
  pswap(a1, b1, w1, w3);
  union { unsigned u[4]; f16x8 v; } r;
  r.u[0] = w0; r.u[1] = w1; r.u[2] = w2; r.u[3] = w3;
  return r.v;
}

// ---------- dense attention: round-11-verified attn_dense7 (45.6 us) ------
__global__ __launch_bounds__(256, 2) void attn_dense7_k(
    const f16* __restrict__ Q, const f16* __restrict__ Km,
    const f16* __restrict__ Vt,
    f16* __restrict__ numOut, float* __restrict__ denOut) {
  __shared__ __align__(16) f16 Kl[2][64 * 128];  // [key][d], XOR-swizzled
  __shared__ __align__(16) f16 Vl[2][128 * 64];  // [d][key], XOR-swizzled
  const int tid = threadIdx.x;
  const int lane = tid & 63, wid = tid >> 6;
  const int la = lane & 31, hi = lane >> 5;
  const int id = blockIdx.x;
  const int grp = id & 15;
  const int h = grp & 1;
  const int z = grp >> 1;
  const int bx = id >> 4;
  const int q0w = bx * 128 + wid * 32;
  const int sb0 = z * (kS / kNS);
  const int nt = (kS / kNS) / 64;  // 16

  f16x8 qb[8];
#pragma unroll
  for (int kk = 0; kk < 8; ++kk)
    qb[kk] = *(const f16x8*)(Q + (size_t)(q0w + la) * kD + h * kDH + kk * 16 +
                             hi * 8);

  int kSrc[4], kDst[4], vSrc[4], vDst[4];
#pragma unroll
  for (int p = 0; p < 4; ++p) {
    int m = wid * 16 + p * 4 + (lane >> 4);
    int s = lane & 15;
    kSrc[p] = (sb0 + m) * kD + h * kDH + 8 * (s ^ (m & 7));
    kDst[p] = m * 128 + 8 * s;
    int cv = p * 256 + tid;
    int d = cv >> 3, sv = cv & 7;
    vSrc[p] = (h * kDH + d) * kS + sb0 + 8 * (sv ^ (d & 7));
    vDst[p] = d * 64 + 8 * sv;
  }

  f32x16 o0 = {}, o1 = {}, o2 = {}, o3 = {};
  float den = 0.0f;
  f16x8 kst[4], vst[4];

#pragma unroll
  for (int p = 0; p < 4; ++p) {
    kst[p] = *(const f16x8*)(Km + kSrc[p]);
    vst[p] = *(const f16x8*)(Vt + vSrc[p]);
  }
#pragma unroll
  for (int p = 0; p < 4; ++p) {
    *(f16x8*)&Kl[0][kDst[p]] = kst[p];
    *(f16x8*)&Vl[0][vDst[p]] = vst[p];
  }
  __syncthreads();

  for (int t = 0; t < nt; ++t) {
    const int cur = t & 1;
    if (t + 1 < nt) {
#pragma unroll
      for (int p = 0; p < 4; ++p) {
        kst[p] = *(const f16x8*)(Km + kSrc[p] + (t + 1) * 64 * kD);
        vst[p] = *(const f16x8*)(Vt + vSrc[p] + (t + 1) * 64);
      }
    }

    f32x16 st0 = {}, st1 = {};
    __builtin_amdgcn_s_setprio(1);
#pragma unroll
    for (int kk = 0; kk < 8; ++kk) {
      int sl = 8 * ((kk * 2 + hi) ^ (la & 7));
      f16x8 k0 = *(const f16x8*)&Kl[cur][la * 128 + sl];
      f16x8 k1 = *(const f16x8*)&Kl[cur][(32 + la) * 128 + sl];
      st0 = MFMA32_F16(k0, qb[kk], st0, 0, 0, 0);
      st1 = MFMA32_F16(k1, qb[kk], st1, 0, 0, 0);
    }
    __builtin_amdgcn_s_setprio(0);

    f32x16 pe0, pe1;
#pragma unroll
    for (int i = 0; i < 16; ++i) {
      pe0[i] = __expf(st0[i] * kScale);
      pe1[i] = __expf(st1[i] * kScale);
    }
#pragma unroll
    for (int i = 0; i < 16; ++i) den += pe0[i] + pe1[i];

    f16x8 pf[4];
    pf[0] = build_pfrag(pe0[0], pe0[1], pe0[2], pe0[3], pe0[4], pe0[5], pe0[6], pe0[7]);
    pf[1] = build_pfrag(pe0[8], pe0[9], pe0[10], pe0[11], pe0[12], pe0[13], pe0[14], pe0[15]);
    pf[2] = build_pfrag(pe1[0], pe1[1], pe1[2], pe1[3], pe1[4], pe1[5], pe1[6], pe1[7]);
    pf[3] = build_pfrag(pe1[8], pe1[9], pe1[10], pe1[11], pe1[12], pe1[13], pe1[14], pe1[15]);

    __builtin_amdgcn_s_setprio(1);
#pragma unroll
    for (int dt = 0; dt < 4; ++dt) {
      int d = dt * 32 + la;
      f32x16* op = (dt == 0) ? &o0 : (dt == 1) ? &o1 : (dt == 2) ? &o2 : &o3;
#pragma unroll
      for (int ks = 0; ks < 4; ++ks) {
        f16x8 vf = *(const f16x8*)&Vl[cur][d * 64 + 8 * ((ks * 2 + hi) ^ (d & 7))];
        *op = MFMA32_F16(vf, pf[ks], *op, 0, 0, 0);
      }
    }
    __builtin_amdgcn_s_setprio(0);

    if (t + 1 < nt) {
      const int nxt = cur ^ 1;
#pragma unroll
      for (int p = 0; p < 4; ++p) {
        *(f16x8*)&Kl[nxt][kDst[p]] = kst[p];
        *(f16x8*)&Vl[nxt][vDst[p]] = vst[p];
      }
      __syncthreads();
    }
  }

  const size_t nbase = ((size_t)z * kH + h) * kL + q0w;
  const size_t rowb = (nbase + la) * kDH;
#pragma unroll
  for (int dt = 0; dt < 4; ++dt) {
    const f32x16* op = (dt == 0) ? &o0 : (dt == 1) ? &o1 : (dt == 2) ? &o2 : &o3;
    unsigned u01 = pkh((*op)[0], (*op)[1]);
    unsigned u23 = pkh((*op)[2], (*op)[3]);
    unsigned u89 = pkh((*op)[4], (*op)[5]);
    unsigned uab = pkh((*op)[6], (*op)[7]);
    unsigned w0, w1, w2, w3;
    pswap(u01, u89, w0, w2);
    pswap(u23, uab, w1, w3);
    union { unsigned u[4]; f16x8 v; } r1;
    r1.u[0] = w0; r1.u[1] = w1; r1.u[2] = w2; r1.u[3] = w3;
    *(f16x8*)&numOut[rowb + dt * 32 + hi * 8] = r1.v;

    unsigned v01 = pkh((*op)[8], (*op)[9]);
    unsigned v23 = pkh((*op)[10], (*op)[11]);
    unsigned v89 = pkh((*op)[12], (*op)[13]);
    unsigned vab = pkh((*op)[14], (*op)[15]);
    unsigned x0, x1, x2, x3;
    pswap(v01, v89, x0, x2);
    pswap(v23, vab, x1, x3);
    union { unsigned u[4]; f16x8 v; } r2;
    r2.u[0] = x0; r2.u[1] = x1; r2.u[2] = x2; r2.u[3] = x3;
    *(f16x8*)&numOut[rowb + dt * 32 + 16 + hi * 8] = r2.v;
  }
  float dq = den + __shfl_xor(den, 32);
  if (lane < 32)
    denOut[((size_t)z * kH + h) * kL + q0w + lane] = dq;
}

// ---------- fused correction + combine (round-11-verified serial form) ----
__global__ __launch_bounds__(256) void corrcomb_k(
    const unsigned int* __restrict__ loopw, const unsigned char* __restrict__ maskb,
    const int* __restrict__ flags,
    const f16* __restrict__ Q, const f16* __restrict__ Km,
    const f16* __restrict__ V,
    const f16* __restrict__ numb, const float* __restrict__ denb,
    f16* __restrict__ out16) {
  __shared__ float cvL[4][128];
  __shared__ float csL[4];
  const int lane = threadIdx.x & 63;
  const int wid = threadIdx.x >> 6;
  const int w = blockIdx.x * 4 + wid;
  const int f = w >> 1, h = w & 1;
  const int lstride = flags[0];
  const int mstride = flags[1];

  int idx = -1, valid = 0;
  if (lane < 32) {
    idx = (int)loopw[(size_t)(f * 32 + lane) * lstride];
    valid = maskb[(size_t)f * mstride] ? 1 : 0;
  }
#pragma unroll
  for (int j = 0; j < 32; ++j) {
    int oidx = __shfl(idx, j);
    if (lane < 32 && j < lane && oidx == idx) valid = 0;
  }

  const size_t qb = (size_t)f * kD + h * kDH + 2 * lane;
  const float qa = (float)Q[qb];
  const float qbv = (float)Q[qb + 1];
  float s0 = 0.0f, cv0 = 0.0f, cv1 = 0.0f;
  for (int e = 0; e < 32; ++e) {
    int ei = __shfl(idx, e);
    int ev = __shfl(valid, e);
    if (!ev) continue;
    size_t kb = (size_t)ei * kD + h * kDH + 2 * lane;
    float part = qa * (float)Km[kb] + qbv * (float)Km[kb + 1];
#pragma unroll
    for (int m = 1; m < 64; m <<= 1) part += __shfl_xor(part, m);
    float pe = __expf(part * kScale);
    s0 += pe;
    cv0 += pe * (float)V[kb];
    cv1 += pe * (float)V[kb + 1];
  }
  cvL[wid][2 * lane] = cv0;
  cvL[wid][2 * lane + 1] = cv1;
  if (lane == 0) csL[wid] = s0;
  __syncthreads();

#pragma unroll
  for (int e = 0; e < 2; ++e) {
    int idx2 = e * 256 + threadIdx.x;
    int floc = idx2 >> 8;
    int c = idx2 & 255;
    int h2 = c >> 7;
    int d = c & 127;
    int widx = floc * 2 + h2;
    int fabs_ = blockIdx.x * 2 + floc;
    float n = -cvL[widx][d];
    float dn = -csL[widx];
#pragma unroll
    for (int z = 0; z < kNS; ++z) {
      n += (float)numb[((size_t)(z * kH + h2) * kL + fabs_) * kDH + d];
      dn += denb[((size_t)z * kH + h2) * kL + fabs_];
    }
    out16[(size_t)fabs_ * kD + h2 * kDH + d] = (f16)(n / dn);
  }
}

extern "C" void kernel_launch(void* const* d_in, const int* in_sizes, int n_in,
                              void* d_out, int out_size, void* d_ws, size_t ws_size,
                              hipStream_t stream) {
  const unsigned int* loopw = (const unsigned int*)d_in[0];
  const unsigned char* fmask = (const unsigned char*)d_in[1];
  const float* edge = (const float*)d_in[2];
  const float* face = (const float*)d_in[3];
  const float* inw = (const float*)d_in[4];
  const float* inb = (const float*)d_in[5];
  const float* outw = (const float*)d_in[6];
  const float* outb = (const float*)d_in[7];
  float* out = (float*)d_out;

  char* p = (char*)d_ws;
  auto alloc = [&](size_t bytes) {
    char* q = p;
    p += (bytes + 255) & ~(size_t)255;
    return q;
  };
  int* flags = (int*)alloc(256);
  f16* e16 = (f16*)alloc((size_t)kS * kD * 2);
  f16* win16 = (f16*)alloc((size_t)kNL * 3 * kD * kD * 2);
  f16* wout16 = (f16*)alloc((size_t)kNL * kD * kD * 2);
  f16* xa = (f16*)alloc((size_t)kL * kD * 2);
  f16* q16 = (f16*)alloc((size_t)kL * kD * 2);
  f16* ao16 = (f16*)alloc((size_t)kL * kD * 2);
  f16* scr16 = (f16*)alloc((size_t)kL * kD * 2);
  f16* wqo = (f16*)alloc((size_t)3 * kD * kD * 2);
  float* bprime = (float*)alloc((size_t)3 * kD * 4);
  f16* k16all = (f16*)alloc((size_t)kNL * kS * kD * 2);
  f16* vt16all = (f16*)alloc((size_t)kNL * kS * kD * 2);
  f16* v16all = (f16*)alloc((size_t)kNL * kS * kD * 2);
  f16* numb = (f16*)alloc((size_t)kNS * kH * kL * kDH * 2);
  float* denb = (float*)alloc((size_t)kNS * kH * kL * 4);

  detect_k<<<1, 256, 0, stream>>>(loopw, fmask, flags);
  cvt_all_k<<<1024, 256, 0, stream>>>(edge, face, inw, outw, e16, xa, win16,
                                      wout16);
  compose_k<<<dim3(256, 3), 256, 0, stream>>>(inw, inb, outw, outb, wqo,
                                              bprime);
  kvall_gemm_k<<<4096, 256, 0, stream>>>(e16, win16, inb, k16all, vt16all,
                                         v16all);

  for (int l = 0; l < kNL; ++l) {
    const f16* kl = k16all + (size_t)l * kS * kD;
    const f16* vtl = vt16all + (size_t)l * kS * kD;
    const f16* vl = v16all + (size_t)l * kS * kD;
    // q_l: layer 0 from face w/ wq_0; else composed from previous O
    if (l == 0) {
      gemm_awt_k<<<dim3(64, 4), 256, 0, stream>>>(
          xa, win16, inb, q16, nullptr, kL, kD, kD);
    } else {
      gemm_awt_k<<<dim3(64, 4), 256, 0, stream>>>(
          ao16, wqo + (size_t)(l - 1) * kD * kD, bprime + (l - 1) * kD, q16,
          nullptr, kL, kD, kD);
    }
    attn_dense7_k<<<512, 256, 0, stream>>>(q16, kl, vtl, numb, denb);
    corrcomb_k<<<kL / 2, 256, 0, stream>>>(loopw, fmask, flags, q16, kl, vl,
                                           numb, denb, ao16);
  }
  // final out-projection (only layer 3's survives composition), f32 output
  gemm_awt_k<<<dim3(64, 4), 256, 0, stream>>>(
      ao16, wout16 + (size_t)3 * kD * kD, outb + 3 * kD, scr16, out, kL, kD,
      kD);
}